// Round 1
// baseline (2002.424 us; speedup 1.0000x reference)
//
#include <hip/hip_runtime.h>

// Performer FastAttention fp32 baseline (fused, 2 kernels + memset).
// B=4,H=16 -> BH=64; N=4096; D=E=64; M=256.

#define BH    64
#define NSEQ  4096
#define DD    64
#define MM    256
#define DN    0.35355339059327373f   // 64^-0.25
#define RATIO 0.0625f                 // 256^-0.5
#define EPS   1e-4f

// ws layout (float units)
#define CTX_OFF  0                       // BH*MM*DD = 1,048,576
#define KSUM_OFF (BH*MM*DD)              // + BH*MM = 16,384
#define VSUM_OFF (KSUM_OFF + BH*MM)      // + BH*DD = 4,096
#define MG_OFF   (VSUM_OFF + BH*DD)      // + 1 (uint-encoded running max)
#define WS_FLOATS (MG_OFF + 4)

__device__ __forceinline__ unsigned ford(float f) {
    unsigned u = __float_as_uint(f);
    return (u & 0x80000000u) ? ~u : (u | 0x80000000u);
}
__device__ __forceinline__ float ford_inv(unsigned u) {
    return (u & 0x80000000u) ? __uint_as_float(u & 0x7fffffffu) : __uint_as_float(~u);
}

// ---------------- keys pass: ctx_raw[m][e] += exp(kd - diag)*v, ksum_raw[m], vsum[e], global max(kd)
// grid: BH*16 chunks of 256 rows; block 256 threads (thread t owns projection row m=t)
__global__ __launch_bounds__(256, 2)
void keys_kernel(const float* __restrict__ kg, const float* __restrict__ vg,
                 const float* __restrict__ pg, float* __restrict__ ws)
{
    __shared__ float projlds[MM * DD];   // 64 KB
    __shared__ float krow[4][DD];
    __shared__ float vrow[4][DD];
    __shared__ float diaglds[4];
    __shared__ float wmaxlds[4];

    const int tid = threadIdx.x;
    const int bh   = blockIdx.x >> 4;
    const int row0 = (blockIdx.x & 15) * 256;

    for (int i = tid; i < MM * DD; i += 256) projlds[i] = pg[i];
    __syncthreads();
    float preg[DD];
#pragma unroll
    for (int d = 0; d < DD; ++d) preg[d] = projlds[tid * DD + d];

    float ctx[DD];
#pragma unroll
    for (int e = 0; e < DD; ++e) ctx[e] = 0.f;
    float ksum = 0.f, mloc = -1e30f, vs = 0.f;

    const int w = tid >> 6, l = tid & 63;
    const long base = (long)(bh * NSEQ + row0) * DD;

    for (int g = 0; g < 64; ++g) {
        const int r = g * 4 + w;
        float kn = kg[base + (long)r * DD + l] * DN;
        float vv = vg[base + (long)r * DD + l];
        krow[w][l] = kn;
        vrow[w][l] = vv;
        float s = kn * kn;
#pragma unroll
        for (int mk = 32; mk >= 1; mk >>= 1) s += __shfl_xor(s, mk, 64);
        if (l == 0) diaglds[w] = 0.5f * s;
        __syncthreads();

        if (tid < DD) vs += vrow[0][tid] + vrow[1][tid] + vrow[2][tid] + vrow[3][tid];

#pragma unroll
        for (int rr = 0; rr < 4; ++rr) {
            float a0 = 0.f, a1 = 0.f, a2 = 0.f, a3 = 0.f;
#pragma unroll
            for (int d = 0; d < DD; d += 4) {
                a0 += krow[rr][d + 0] * preg[d + 0];
                a1 += krow[rr][d + 1] * preg[d + 1];
                a2 += krow[rr][d + 2] * preg[d + 2];
                a3 += krow[rr][d + 3] * preg[d + 3];
            }
            const float kd = (a0 + a1) + (a2 + a3);
            mloc = fmaxf(mloc, kd);
            const float wv = __expf(kd - diaglds[rr]);
            ksum += wv;
#pragma unroll
            for (int e = 0; e < DD; ++e) ctx[e] += wv * vrow[rr][e];
        }
        __syncthreads();
    }

    float* ctxraw = ws + CTX_OFF + (size_t)bh * MM * DD;
#pragma unroll
    for (int e = 0; e < DD; ++e) atomicAdd(&ctxraw[tid * DD + e], ctx[e]);
    atomicAdd(&ws[KSUM_OFF + bh * MM + tid], ksum);
    if (tid < DD) atomicAdd(&ws[VSUM_OFF + bh * DD + tid], vs);

#pragma unroll
    for (int mk = 32; mk >= 1; mk >>= 1) mloc = fmaxf(mloc, __shfl_xor(mloc, mk, 64));
    if (l == 0) wmaxlds[w] = mloc;
    __syncthreads();
    if (tid == 0) {
        const float mm = fmaxf(fmaxf(wmaxlds[0], wmaxlds[1]), fmaxf(wmaxlds[2], wmaxlds[3]));
        atomicMax((unsigned*)&ws[MG_OFF], ford(mm));
    }
}

// ---------------- query pass: per-row max, t = exp(kd-diag-mrow)+eps; out = (t·ctx)/(t·ksum)
// grid: BH*8 chunks of 512 rows; block 512 threads (thread owns one q row)
__global__ __launch_bounds__(512, 1)
void query_kernel(const float* __restrict__ qg, const float* __restrict__ pg,
                  const float* __restrict__ ws, float* __restrict__ out)
{
    __shared__ float projlds[MM * DD];   // 64 KB
    __shared__ float bbuf[256 * 65];     // 66.5 KB: q staging (padded), then ctx[256][64]
    __shared__ float ksumlds[MM];

    const int tid = threadIdx.x;
    const int bh   = blockIdx.x >> 3;
    const int row0 = (blockIdx.x & 7) * 512;
    const long qbase = (long)(bh * NSEQ + row0) * DD;

    for (int i = tid; i < MM * DD; i += 512) projlds[i] = pg[i];

    // stage q rows 0..255 (padded stride 65 -> conflict-free row reads)
    for (int i = tid; i < 256 * DD; i += 512) {
        bbuf[(i >> 6) * 65 + (i & 63)] = qg[qbase + i];
    }
    __syncthreads();
    float qreg[DD];
    float diag = 0.f;
    if (tid < 256) {
#pragma unroll
        for (int d = 0; d < DD; ++d) {
            const float x = bbuf[tid * 65 + d] * DN;
            qreg[d] = x; diag += x * x;
        }
    }
    __syncthreads();
    // stage q rows 256..511
    for (int i = tid; i < 256 * DD; i += 512) {
        bbuf[(i >> 6) * 65 + (i & 63)] = qg[qbase + 256 * DD + i];
    }
    __syncthreads();
    if (tid >= 256) {
#pragma unroll
        for (int d = 0; d < DD; ++d) {
            const float x = bbuf[(tid - 256) * 65 + d] * DN;
            qreg[d] = x; diag += x * x;
        }
    }
    diag *= 0.5f;
    __syncthreads();

    // stage true context/ksum (fold ratio, exp(-m_global), eps terms)
    const float mg = ford_inv(((const unsigned*)ws)[MG_OFF]);
    const float cs = RATIO * __expf(-mg);
    const float ce = RATIO * EPS;
    const float* ctxraw = ws + CTX_OFF + (size_t)bh * MM * DD;
    for (int i = tid; i < MM * DD; i += 512) {
        bbuf[i] = cs * ctxraw[i] + ce * ws[VSUM_OFF + bh * DD + (i & 63)];
    }
    for (int i = tid; i < MM; i += 512) {
        ksumlds[i] = cs * ws[KSUM_OFF + bh * MM + i] + ce * (float)NSEQ;
    }
    __syncthreads();

    // pass A: per-row max of kd
    float mrow = -1e30f;
    for (int m = 0; m < MM; ++m) {
        float a0 = 0.f, a1 = 0.f, a2 = 0.f, a3 = 0.f;
#pragma unroll
        for (int d = 0; d < DD; d += 4) {
            a0 += qreg[d + 0] * projlds[m * DD + d + 0];
            a1 += qreg[d + 1] * projlds[m * DD + d + 1];
            a2 += qreg[d + 2] * projlds[m * DD + d + 2];
            a3 += qreg[d + 3] * projlds[m * DD + d + 3];
        }
        mrow = fmaxf(mrow, (a0 + a1) + (a2 + a3));
    }

    // pass B: recompute kd, accumulate num/den (q-side ratio cancels in the division)
    float num[DD];
#pragma unroll
    for (int e = 0; e < DD; ++e) num[e] = 0.f;
    float den = 0.f;
    for (int m = 0; m < MM; ++m) {
        float a0 = 0.f, a1 = 0.f, a2 = 0.f, a3 = 0.f;
#pragma unroll
        for (int d = 0; d < DD; d += 4) {
            a0 += qreg[d + 0] * projlds[m * DD + d + 0];
            a1 += qreg[d + 1] * projlds[m * DD + d + 1];
            a2 += qreg[d + 2] * projlds[m * DD + d + 2];
            a3 += qreg[d + 3] * projlds[m * DD + d + 3];
        }
        const float kd = (a0 + a1) + (a2 + a3);
        const float t = __expf(kd - diag - mrow) + EPS;
        den += t * ksumlds[m];
#pragma unroll
        for (int e = 0; e < DD; ++e) num[e] += t * bbuf[m * DD + e];
    }

    const float dinv = 1.0f / den;
    float* op = out + qbase + (long)tid * DD;
#pragma unroll
    for (int e = 0; e < DD; ++e) op[e] = num[e] * dinv;
}

extern "C" void kernel_launch(void* const* d_in, const int* in_sizes, int n_in,
                              void* d_out, int out_size, void* d_ws, size_t ws_size,
                              hipStream_t stream)
{
    const float* q = (const float*)d_in[0];
    const float* k = (const float*)d_in[1];
    const float* v = (const float*)d_in[2];
    const float* p = (const float*)d_in[3];
    float* ws  = (float*)d_ws;
    float* out = (float*)d_out;

    hipMemsetAsync(d_ws, 0, (size_t)WS_FLOATS * sizeof(float), stream);
    keys_kernel<<<dim3(BH * 16), dim3(256), 0, stream>>>(k, v, p, ws);
    query_kernel<<<dim3(BH * 8), dim3(512), 0, stream>>>(q, p, ws, out);
}

// Round 3
// 760.957 us; speedup vs baseline: 2.6315x; 2.6315x over previous
//
#include <hip/hip_runtime.h>

// Performer FastAttention — MFMA bf16 (hi/lo split for S-GEMMs).
// B=4,H=16 -> BH=64; N=4096; D=E=64; M=256.

#define BH    64
#define NSEQ  4096
#define DD    64
#define MM    256
#define DN    0.35355339059327373f   // 64^-0.25
#define RATIO 0.0625f                 // 256^-0.5
#define EPS   1e-4f

// ws layout (float units): ctxT[bh][e][m], ksum[bh][m], vsum[bh][e], mg
#define CTX_OFF  0
#define KSUM_OFF (BH*MM*DD)
#define VSUM_OFF (KSUM_OFF + BH*MM)
#define MG_OFF   (VSUM_OFF + BH*DD)
#define WS_FLOATS (MG_OFF + 4)

typedef __attribute__((ext_vector_type(8)))  short bf16x8;
typedef __attribute__((ext_vector_type(16))) float f32x16;

#define MFMA(a,b,c) __builtin_amdgcn_mfma_f32_32x32x16_bf16((a),(b),(c),0,0,0)

__device__ __forceinline__ unsigned short f2bf(float x) {
    unsigned u = __float_as_uint(x);
    return (unsigned short)((u + 0x7fffu + ((u >> 16) & 1u)) >> 16);
}
__device__ __forceinline__ void split8(const float* x, bf16x8& hv, bf16x8& lv) {
#pragma unroll
    for (int i = 0; i < 8; ++i) {
        unsigned short hb = f2bf(x[i]);
        float hf = __uint_as_float(((unsigned)hb) << 16);
        hv[i] = (short)hb;
        lv[i] = (short)f2bf(x[i] - hf);
    }
}
__device__ __forceinline__ unsigned ford(float f) {
    unsigned u = __float_as_uint(f);
    return (u & 0x80000000u) ? ~u : (u | 0x80000000u);
}
__device__ __forceinline__ float ford_inv(unsigned u) {
    return (u & 0x80000000u) ? __uint_as_float(u & 0x7fffffffu) : __uint_as_float(~u);
}

// ============================ KEYS ============================
// grid 512 = bh(64) x seg(8); block 512 = 8 waves; each block: 512 k-rows (8 chunks of 64)
__global__ __launch_bounds__(512)
void keys_kernel(const float* __restrict__ kg, const float* __restrict__ vg,
                 const float* __restrict__ pg, float* __restrict__ ws)
{
    __shared__ __align__(16) short projh[MM*72];
    __shared__ __align__(16) short projl[MM*72];
    __shared__ __align__(16) short klh[64*72];
    __shared__ __align__(16) short kll[64*72];
    __shared__ __align__(16) short vT[64*72];
    __shared__ __align__(16) short wlds[MM*72];
    __shared__ float diagl[64];
    __shared__ float vswr[8][64];

    const int tid  = threadIdx.x;
    const int wv   = tid >> 6;
    const int lane = tid & 63;
    const int l31  = lane & 31;
    const int h    = lane >> 5;
    const int bh   = blockIdx.x >> 3;
    const int seg  = blockIdx.x & 7;

    // stage projection hi/lo (once per block)
    {
        const int m  = tid >> 1;
        const int dbase = (tid & 1) * 32;
        const int sw = (m & 7) << 3;
#pragma unroll
        for (int b = 0; b < 4; ++b) {
            const int d0 = dbase + 8*b;
            float x[8];
            *(float4*)&x[0] = *(const float4*)(pg + m*64 + d0);
            *(float4*)&x[4] = *(const float4*)(pg + m*64 + d0 + 4);
            bf16x8 hv, lv; split8(x, hv, lv);
            *(bf16x8*)&projh[m*72 + (d0 ^ sw)] = hv;
            *(bf16x8*)&projl[m*72 + (d0 ^ sw)] = lv;
        }
    }
    __syncthreads();

    // cache proj B-fragments for this wave's m-tile (m = l31 + 32*wv)
    bf16x8 pBh[4], pBl[4];
    {
        const int m  = l31 + 32*wv;
        const int sw = (m & 7) << 3;
#pragma unroll
        for (int ks = 0; ks < 4; ++ks) {
            const int d0 = 16*ks + 8*h;
            pBh[ks] = *(const bf16x8*)&projh[m*72 + (d0 ^ sw)];
            pBl[ks] = *(const bf16x8*)&projl[m*72 + (d0 ^ sw)];
        }
    }

    f32x16 cacc0, cacc1;
#pragma unroll
    for (int i = 0; i < 16; ++i) { cacc0[i] = 0.f; cacc1[i] = 0.f; }
    float ksacc = 0.f, mloc = -3e38f;
    float vsacc[8];
#pragma unroll
    for (int i = 0; i < 8; ++i) vsacc[i] = 0.f;

    const int mcol = l31 + 32*wv;
    const int swm  = (l31 & 7) << 3;

    for (int ch = 0; ch < 8; ++ch) {
        const int row0 = seg*512 + ch*64;
        const size_t base = ((size_t)(bh*NSEQ + row0)) * DD;

        // ---- stage k~ hi/lo, vT (transposed bf16), diag ----
        {
            const int n  = tid >> 3;
            const int d0 = (tid & 7) * 8;
            float x[8];
            *(float4*)&x[0] = *(const float4*)(kg + base + n*64 + d0);
            *(float4*)&x[4] = *(const float4*)(kg + base + n*64 + d0 + 4);
            float ss = 0.f;
#pragma unroll
            for (int i = 0; i < 8; ++i) { x[i] *= DN; ss += x[i]*x[i]; }
            ss += __shfl_xor(ss, 1); ss += __shfl_xor(ss, 2); ss += __shfl_xor(ss, 4);
            if ((lane & 7) == 0) diagl[n] = 0.5f * ss;
            bf16x8 hv, lv; split8(x, hv, lv);
            const int sw = (n & 7) << 3;
            *(bf16x8*)&klh[n*72 + (d0 ^ sw)] = hv;
            *(bf16x8*)&kll[n*72 + (d0 ^ sw)] = lv;
            float y[8];
            *(float4*)&y[0] = *(const float4*)(vg + base + n*64 + d0);
            *(float4*)&y[4] = *(const float4*)(vg + base + n*64 + d0 + 4);
#pragma unroll
            for (int i = 0; i < 8; ++i) {
                vsacc[i] += y[i];
                vT[(d0+i)*72 + (n ^ (i<<3))] = (short)f2bf(y[i]);
            }
        }
        __syncthreads();

        // ---- S-GEMM (split 3-term): C[n][m], wave owns m-tile ----
        f32x16 s0, s1;
#pragma unroll
        for (int i = 0; i < 16; ++i) { s0[i] = 0.f; s1[i] = 0.f; }
#pragma unroll
        for (int ks = 0; ks < 4; ++ks) {
            const int d0 = 16*ks + 8*h;
            const int n0 = l31, n1 = l31 + 32;
            const int sw0 = (n0 & 7) << 3, sw1 = (n1 & 7) << 3;
            bf16x8 a0h = *(const bf16x8*)&klh[n0*72 + (d0 ^ sw0)];
            bf16x8 a0l = *(const bf16x8*)&kll[n0*72 + (d0 ^ sw0)];
            bf16x8 a1h = *(const bf16x8*)&klh[n1*72 + (d0 ^ sw1)];
            bf16x8 a1l = *(const bf16x8*)&kll[n1*72 + (d0 ^ sw1)];
            s0 = MFMA(a0h, pBh[ks], s0);
            s1 = MFMA(a1h, pBh[ks], s1);
            s0 = MFMA(a0l, pBh[ks], s0);
            s1 = MFMA(a1l, pBh[ks], s1);
            s0 = MFMA(a0h, pBl[ks], s0);
            s1 = MFMA(a1h, pBl[ks], s1);
        }

        // ---- epilogue: w = exp(S - diag); track global max & ksum; w -> wlds ----
        {
            float kpart = 0.f;
#pragma unroll
            for (int nt = 0; nt < 2; ++nt) {
#pragma unroll
                for (int r = 0; r < 16; ++r) {
                    const int n = 32*nt + (r&3) + 8*(r>>2) + 4*h;
                    const float sv = nt ? s1[r] : s0[r];
                    mloc = fmaxf(mloc, sv);
                    const float w = __expf(sv - diagl[n]);
                    kpart += w;
                    wlds[mcol*72 + (n ^ swm)] = (short)f2bf(w);
                }
            }
            ksacc += kpart;
        }
        __syncthreads();

        // ---- ctx GEMM: C[m][e] += A(w[m][n]) * B(v[n][e]) ----
#pragma unroll
        for (int ks = 0; ks < 4; ++ks) {
            const int n0 = 16*ks + 8*h;
            bf16x8 aW = *(const bf16x8*)&wlds[mcol*72 + (n0 ^ swm)];
            const int e0 = l31, e1 = l31 + 32;
            bf16x8 b0 = *(const bf16x8*)&vT[e0*72 + (n0 ^ ((e0&7)<<3))];
            bf16x8 b1 = *(const bf16x8*)&vT[e1*72 + (n0 ^ ((e1&7)<<3))];
            cacc0 = MFMA(aW, b0, cacc0);
            cacc1 = MFMA(aW, b1, cacc1);
        }
        __syncthreads();
    }

    // ---- final reductions ----
    ksacc += __shfl_xor(ksacc, 32);
    if (lane < 32) atomicAdd(&ws[KSUM_OFF + bh*MM + mcol], ksacc);

#pragma unroll
    for (int m = 1; m <= 32; m <<= 1) mloc = fmaxf(mloc, __shfl_xor(mloc, m));
    if (lane == 0) atomicMax((unsigned*)&ws[MG_OFF], ford(mloc));

#pragma unroll
    for (int et = 0; et < 2; ++et) {
        const int e = l31 + 32*et;
#pragma unroll
        for (int r = 0; r < 16; ++r) {
            const int m = 32*wv + (r&3) + 8*(r>>2) + 4*h;
            atomicAdd(&ws[CTX_OFF + bh*(MM*DD) + e*MM + m], et ? cacc1[r] : cacc0[r]);
        }
    }

#pragma unroll
    for (int i = 0; i < 8; ++i) {
        float v = vsacc[i];
        v += __shfl_xor(v, 8); v += __shfl_xor(v, 16); v += __shfl_xor(v, 32);
        vsacc[i] = v;
    }
    if (lane < 8) {
#pragma unroll
        for (int i = 0; i < 8; ++i) vswr[wv][lane*8 + i] = vsacc[i];
    }
    __syncthreads();
    if (tid < 64) {
        float s = 0.f;
#pragma unroll
        for (int w = 0; w < 8; ++w) s += vswr[w][tid];
        atomicAdd(&ws[VSUM_OFF + bh*DD + tid], s);
    }
}

// ============================ QUERY ============================
// grid 512 = bh(64) x seg(8); block 512 = 8 waves; each block: 512 q-rows (4 chunks of 128)
__global__ __launch_bounds__(512)
void query_kernel(const float* __restrict__ qg, const float* __restrict__ pg,
                  const float* __restrict__ ws, float* __restrict__ out)
{
    __shared__ __align__(16) short projh[MM*72];
    __shared__ __align__(16) short projl[MM*72];
    __shared__ __align__(16) short ctxb[64*264];     // rows e, cols m (bf16, folded)
    __shared__ __align__(16) short qbuf[2*128*72];   // q~ hi/lo; reused as t[128][136]
    __shared__ float ksuml[MM];
    __shared__ float diagl[128];
    __shared__ float wred[8][128];
    __shared__ float mrowl[128];
    __shared__ float denl[128];

    const int tid  = threadIdx.x;
    const int wv   = tid >> 6;
    const int lane = tid & 63;
    const int l31  = lane & 31;
    const int h    = lane >> 5;
    const int bh   = blockIdx.x >> 3;
    const int seg  = blockIdx.x & 7;

    const float mg = ford_inv(*(const unsigned*)&ws[MG_OFF]);
    const float cs = RATIO * __expf(-mg);
    const float ce = RATIO * EPS;

    // proj staging (same as keys)
    {
        const int m  = tid >> 1;
        const int dbase = (tid & 1) * 32;
        const int sw = (m & 7) << 3;
#pragma unroll
        for (int b = 0; b < 4; ++b) {
            const int d0 = dbase + 8*b;
            float x[8];
            *(float4*)&x[0] = *(const float4*)(pg + m*64 + d0);
            *(float4*)&x[4] = *(const float4*)(pg + m*64 + d0 + 4);
            bf16x8 hv, lv; split8(x, hv, lv);
            *(bf16x8*)&projh[m*72 + (d0 ^ sw)] = hv;
            *(bf16x8*)&projl[m*72 + (d0 ^ sw)] = lv;
        }
    }
    // ctxb staging: true ctx (fold cs, ce*vsum), bf16, rows e cols m
    {
        const int e  = tid >> 3;
        const int m0 = (tid & 7) * 32;
        const float vs = ws[VSUM_OFF + bh*DD + e];
        const int sw = (e & 7) << 3;
#pragma unroll
        for (int b = 0; b < 4; ++b) {
            float x[8];
            *(float4*)&x[0] = *(const float4*)(ws + CTX_OFF + bh*(MM*DD) + e*MM + m0 + 8*b);
            *(float4*)&x[4] = *(const float4*)(ws + CTX_OFF + bh*(MM*DD) + e*MM + m0 + 8*b + 4);
            bf16x8 v;
#pragma unroll
            for (int j = 0; j < 8; ++j) v[j] = (short)f2bf(cs * x[j] + ce * vs);
            *(bf16x8*)&ctxb[e*264 + ((m0 + 8*b) ^ sw)] = v;
        }
    }
    if (tid < 256) ksuml[tid] = cs * ws[KSUM_OFF + bh*MM + tid] + ce * (float)NSEQ;
    __syncthreads();

    bf16x8 pBh[4], pBl[4];
    {
        const int m  = l31 + 32*wv;
        const int sw = (m & 7) << 3;
#pragma unroll
        for (int ks = 0; ks < 4; ++ks) {
            const int d0 = 16*ks + 8*h;
            pBh[ks] = *(const bf16x8*)&projh[m*72 + (d0 ^ sw)];
            pBl[ks] = *(const bf16x8*)&projl[m*72 + (d0 ^ sw)];
        }
    }

    short* tl = qbuf;   // t[128][136] alias (valid after S phase)
    const int mcol = l31 + 32*wv;
    const int nt = wv & 3, et = wv >> 2;
    const int arow = l31 + 32*nt;
    const int swa = (arow & 7) << 3;
    const int erow = l31 + 32*et;
    const int swe = (erow & 7) << 3;

    for (int ch = 0; ch < 4; ++ch) {
        const int row0 = seg*512 + ch*128;
        const size_t base = ((size_t)(bh*NSEQ + row0)) * DD;

        // ---- stage q~ hi/lo + diag ----
        {
            const int n  = tid >> 2;
            const int d2 = (tid & 3) * 16;
            const int sw = (n & 7) << 3;
            float ss = 0.f;
#pragma unroll
            for (int b = 0; b < 2; ++b) {
                const int d0 = d2 + 8*b;
                float x[8];
                *(float4*)&x[0] = *(const float4*)(qg + base + n*64 + d0);
                *(float4*)&x[4] = *(const float4*)(qg + base + n*64 + d0 + 4);
#pragma unroll
                for (int i = 0; i < 8; ++i) { x[i] *= DN; ss += x[i]*x[i]; }
                bf16x8 hv, lv; split8(x, hv, lv);
                *(bf16x8*)&qbuf[n*72 + (d0 ^ sw)] = hv;
                *(bf16x8*)&qbuf[9216 + n*72 + (d0 ^ sw)] = lv;
            }
            ss += __shfl_xor(ss, 1); ss += __shfl_xor(ss, 2);
            if ((lane & 3) == 0) diagl[n] = 0.5f * ss;
        }
        __syncthreads();

        // ---- S-GEMM (split): 4 n-tiles, wave's m-tile ----
        f32x16 s0, s1, s2, s3;
#pragma unroll
        for (int i = 0; i < 16; ++i) { s0[i]=0.f; s1[i]=0.f; s2[i]=0.f; s3[i]=0.f; }
#pragma unroll
        for (int ks = 0; ks < 4; ++ks) {
            const int d0 = 16*ks + 8*h;
#pragma unroll
            for (int t4 = 0; t4 < 4; ++t4) {
                const int n = l31 + 32*t4;
                const int sw = (n & 7) << 3;
                bf16x8 ah = *(const bf16x8*)&qbuf[n*72 + (d0 ^ sw)];
                bf16x8 al = *(const bf16x8*)&qbuf[9216 + n*72 + (d0 ^ sw)];
                if (t4 == 0) { s0 = MFMA(ah, pBh[ks], s0); s0 = MFMA(al, pBh[ks], s0); s0 = MFMA(ah, pBl[ks], s0); }
                else if (t4 == 1) { s1 = MFMA(ah, pBh[ks], s1); s1 = MFMA(al, pBh[ks], s1); s1 = MFMA(ah, pBl[ks], s1); }
                else if (t4 == 2) { s2 = MFMA(ah, pBh[ks], s2); s2 = MFMA(al, pBh[ks], s2); s2 = MFMA(ah, pBl[ks], s2); }
                else              { s3 = MFMA(ah, pBh[ks], s3); s3 = MFMA(al, pBh[ks], s3); s3 = MFMA(ah, pBl[ks], s3); }
            }
        }

        // ---- per-row max over wave's 32 m -> wred ----
#pragma unroll
        for (int t4 = 0; t4 < 4; ++t4) {
#pragma unroll
            for (int r = 0; r < 16; ++r) {
                float v = t4==0 ? s0[r] : (t4==1 ? s1[r] : (t4==2 ? s2[r] : s3[r]));
                v = fmaxf(v, __shfl_xor(v, 1));
                v = fmaxf(v, __shfl_xor(v, 2));
                v = fmaxf(v, __shfl_xor(v, 4));
                v = fmaxf(v, __shfl_xor(v, 8));
                v = fmaxf(v, __shfl_xor(v, 16));
                if (l31 == 0) wred[wv][32*t4 + (r&3) + 8*(r>>2) + 4*h] = v;
            }
        }
        __syncthreads();
        if (tid < 128) {
            float m = wred[0][tid];
#pragma unroll
            for (int w = 1; w < 8; ++w) m = fmaxf(m, wred[w][tid]);
            mrowl[tid] = m;
        }
        __syncthreads();

        // ---- t = exp(S - diag - mrow) + EPS; den partials; waves 0..3 write t half0 ----
        const float kk = ksuml[mcol];
#pragma unroll
        for (int t4 = 0; t4 < 4; ++t4) {
#pragma unroll
            for (int r = 0; r < 16; ++r) {
                const int n = 32*t4 + (r&3) + 8*(r>>2) + 4*h;
                const float svv = t4==0 ? s0[r] : (t4==1 ? s1[r] : (t4==2 ? s2[r] : s3[r]));
                const float t = __expf(svv - diagl[n] - mrowl[n]) + EPS;
                if (t4 == 0) s0[r] = t; else if (t4 == 1) s1[r] = t;
                else if (t4 == 2) s2[r] = t; else s3[r] = t;
                float d = t * kk;
                d += __shfl_xor(d, 1); d += __shfl_xor(d, 2); d += __shfl_xor(d, 4);
                d += __shfl_xor(d, 8); d += __shfl_xor(d, 16);
                if (l31 == 0) wred[wv][n] = d;
            }
        }
        if (wv < 4) {
#pragma unroll
            for (int t4 = 0; t4 < 4; ++t4) {
#pragma unroll
                for (int r = 0; r < 16; ++r) {
                    const int n = 32*t4 + (r&3) + 8*(r>>2) + 4*h;
                    const float t = t4==0 ? s0[r] : (t4==1 ? s1[r] : (t4==2 ? s2[r] : s3[r]));
                    tl[n*136 + (mcol ^ ((n&7)<<3))] = (short)f2bf(t);
                }
            }
        }
        __syncthreads();
        if (tid < 128) {
            float d = 0.f;
#pragma unroll
            for (int w = 0; w < 8; ++w) d += wred[w][tid];
            denl[tid] = d;
        }

        // ---- num GEMM, m-half 0 (ks 0..7) ----
        f32x16 nacc;
#pragma unroll
        for (int i = 0; i < 16; ++i) nacc[i] = 0.f;
#pragma unroll
        for (int ks = 0; ks < 8; ++ks) {
            const int k0 = 16*ks + 8*h;
            bf16x8 aT = *(const bf16x8*)&tl[arow*136 + (k0 ^ swa)];
            bf16x8 bC = *(const bf16x8*)&ctxb[erow*264 + (k0 ^ swe)];
            nacc = MFMA(aT, bC, nacc);
        }
        __syncthreads();

        // ---- waves 4..7 write t half1 ----
        if (wv >= 4) {
#pragma unroll
            for (int t4 = 0; t4 < 4; ++t4) {
#pragma unroll
                for (int r = 0; r < 16; ++r) {
                    const int n = 32*t4 + (r&3) + 8*(r>>2) + 4*h;
                    const float t = t4==0 ? s0[r] : (t4==1 ? s1[r] : (t4==2 ? s2[r] : s3[r]));
                    tl[n*136 + ((mcol-128) ^ ((n&7)<<3))] = (short)f2bf(t);
                }
            }
        }
        __syncthreads();

        // ---- num GEMM, m-half 1 (ks 8..15) ----
#pragma unroll
        for (int ks = 8; ks < 16; ++ks) {
            const int k0  = 16*ks + 8*h;
            const int k0t = 16*(ks-8) + 8*h;
            bf16x8 aT = *(const bf16x8*)&tl[arow*136 + (k0t ^ swa)];
            bf16x8 bC = *(const bf16x8*)&ctxb[erow*264 + (k0 ^ swe)];
            nacc = MFMA(aT, bC, nacc);
        }

        // ---- out = num / den ----
#pragma unroll
        for (int r = 0; r < 16; ++r) {
            const int n = 32*nt + (r&3) + 8*(r>>2) + 4*h;
            out[base + (size_t)n*64 + erow] = nacc[r] / denl[n];
        }
        __syncthreads();
    }
}

extern "C" void kernel_launch(void* const* d_in, const int* in_sizes, int n_in,
                              void* d_out, int out_size, void* d_ws, size_t ws_size,
                              hipStream_t stream)
{
    const float* q = (const float*)d_in[0];
    const float* k = (const float*)d_in[1];
    const float* v = (const float*)d_in[2];
    const float* p = (const float*)d_in[3];
    float* ws  = (float*)d_ws;
    float* out = (float*)d_out;

    (void)hipMemsetAsync(d_ws, 0, (size_t)WS_FLOATS * sizeof(float), stream);
    keys_kernel<<<dim3(512), dim3(512), 0, stream>>>(k, v, p, ws);
    query_kernel<<<dim3(512), dim3(512), 0, stream>>>(q, p, ws, out);
}

// Round 4
// 344.574 us; speedup vs baseline: 5.8113x; 2.2084x over previous
//
#include <hip/hip_runtime.h>
#include <hip/hip_bf16.h>

// Performer FastAttention — MFMA bf16, register-resident softmax (swapped-S layout).
// B=4,H=16 -> BH=64; N=4096; D=E=64; M=256.

#define BH    64
#define NSEQ  4096
#define DD    64
#define MM    256
#define DN    0.35355339059327373f   // 64^-0.25
#define RATIO 0.0625f                 // 256^-0.5
#define EPS   1e-4f

// ws layout (float units): ctx_raw[bh][m][e], ksum_raw[bh][m], vsum_raw[bh][e], mg
#define CTX_OFF  0
#define KSUM_OFF (BH*MM*DD)
#define VSUM_OFF (KSUM_OFF + BH*MM)
#define MG_OFF   (VSUM_OFF + BH*DD)
#define WS_FLOATS (MG_OFF + 4)

typedef __attribute__((ext_vector_type(8)))  short bf16x8;
typedef __attribute__((ext_vector_type(16))) float f32x16;

#define MFMA(a,b,c) __builtin_amdgcn_mfma_f32_32x32x16_bf16((a),(b),(c),0,0,0)
#define PATROW(r,h) ((((r)&3) + 8*((r)>>2)) + 4*(h))

__device__ __forceinline__ unsigned short f2bf(float x) {
    unsigned u = __float_as_uint(x);
    return (unsigned short)((u + 0x7fffu + ((u >> 16) & 1u)) >> 16);
}
__device__ __forceinline__ void split8(const float* x, bf16x8& hv, bf16x8& lv) {
#pragma unroll
    for (int i = 0; i < 8; ++i) {
        unsigned short hb = f2bf(x[i]);
        float hf = __uint_as_float(((unsigned)hb) << 16);
        hv[i] = (short)hb;
        lv[i] = (short)f2bf(x[i] - hf);
    }
}
__device__ __forceinline__ unsigned ford(float f) {
    unsigned u = __float_as_uint(f);
    return (u & 0x80000000u) ? ~u : (u | 0x80000000u);
}
__device__ __forceinline__ float ford_inv(unsigned u) {
    return (u & 0x80000000u) ? __uint_as_float(u & 0x7fffffffu) : __uint_as_float(~u);
}
__device__ __forceinline__ unsigned pkbf(float lo, float hi) {
    union { __hip_bfloat162 b2; unsigned u; } cvt;
    cvt.b2 = __float22bfloat162_rn(make_float2(lo, hi));
    return cvt.u;
}
// C-layout tile (16 f32, rows = PATROW(r,h), col = l31) -> A-operand bf16 fragment
// for k-slice covering local rows BASE*2..BASE*2+15 (BASE=0 -> regs 0-7, BASE=8 -> regs 8-15).
template<int BASE>
__device__ __forceinline__ bf16x8 repack8(const f32x16& a, int h) {
    unsigned X0 = pkbf(a[BASE+0], a[BASE+1]);
    unsigned X1 = pkbf(a[BASE+2], a[BASE+3]);
    unsigned Y0 = pkbf(a[BASE+4], a[BASE+5]);
    unsigned Y1 = pkbf(a[BASE+6], a[BASE+7]);
    unsigned tX0 = (unsigned)__shfl_xor((int)X0, 32);
    unsigned tX1 = (unsigned)__shfl_xor((int)X1, 32);
    unsigned tY0 = (unsigned)__shfl_xor((int)Y0, 32);
    unsigned tY1 = (unsigned)__shfl_xor((int)Y1, 32);
    union { unsigned w[4]; bf16x8 v; } r;
    r.w[0] = h ? tY0 : X0;
    r.w[1] = h ? tY1 : X1;
    r.w[2] = h ? Y0 : tX0;
    r.w[3] = h ? Y1 : tX1;
    return r.v;
}

// ============================ KEYS ============================
// grid 256 = bh(64) x seg(4); block 512 = 8 waves; 16 chunks x 64 k-rows.
// S = D[n][m] (A=k~ rows, B=proj cols); w=exp(S-diag) in regs; in-register repack
// -> ctx GEMM D[m][e]. ctx accumulated in regs -> LDS -> coalesced atomicAdd.
__global__ __launch_bounds__(512)
void keys_kernel(const float* __restrict__ kg, const float* __restrict__ vg,
                 const float* __restrict__ pg, float* __restrict__ ws)
{
    __shared__ __align__(16) short kfh[2][64*64];
    __shared__ __align__(16) short kfl[2][64*64];
    __shared__ __align__(16) short vT [2][64*72];
    __shared__ float diagl[2][64];
    __shared__ float ctxred[MM*DD];   // 64 KB
    __shared__ float vswr[8][64];

    const int tid  = threadIdx.x;
    const int wv   = tid >> 6;
    const int lane = tid & 63;
    const int l31  = lane & 31;
    const int h    = lane >> 5;
    const int bh   = blockIdx.x >> 2;
    const int seg  = blockIdx.x & 3;

    // proj B-fragments (col m = 32*wv + l31) straight from global
    bf16x8 pBh[4], pBl[4];
    {
        const int m = 32*wv + l31;
#pragma unroll
        for (int ks = 0; ks < 4; ++ks) {
            const int d0 = 16*ks + 8*h;
            float x[8];
            *(float4*)&x[0] = *(const float4*)(pg + m*64 + d0);
            *(float4*)&x[4] = *(const float4*)(pg + m*64 + d0 + 4);
            split8(x, pBh[ks], pBl[ks]);
        }
    }

    f32x16 cacc0, cacc1;
#pragma unroll
    for (int i = 0; i < 16; ++i) { cacc0[i] = 0.f; cacc1[i] = 0.f; }
    float ksacc = 0.f, mloc = -3e38f;
    float vsacc[8];
#pragma unroll
    for (int i = 0; i < 8; ++i) vsacc[i] = 0.f;

    auto stage = [&](int ch, int p) {
        const int n = tid >> 3, dg = tid & 7, d0 = dg*8;
        const size_t base = ((size_t)(bh*NSEQ + seg*1024 + ch*64 + n)) * DD;
        float x[8];
        *(float4*)&x[0] = *(const float4*)(kg + base + d0);
        *(float4*)&x[4] = *(const float4*)(kg + base + d0 + 4);
        float ss = 0.f;
#pragma unroll
        for (int i = 0; i < 8; ++i) { x[i] *= DN; ss += x[i]*x[i]; }
        ss += __shfl_xor(ss, 1); ss += __shfl_xor(ss, 2); ss += __shfl_xor(ss, 4);
        if (dg == 0) diagl[p][n] = 0.5f * ss;
        bf16x8 hv, lv; split8(x, hv, lv);
        const int ofs = dg*512 + ((n*8) ^ (dg*8));   // group (ks*2+h)=dg, dg-XOR bank swizzle
        *(bf16x8*)&kfh[p][ofs] = hv;
        *(bf16x8*)&kfl[p][ofs] = lv;
        float y[8];
        *(float4*)&y[0] = *(const float4*)(vg + base + d0);
        *(float4*)&y[4] = *(const float4*)(vg + base + d0 + 4);
#pragma unroll
        for (int i = 0; i < 8; ++i) {
            vsacc[i] += y[i];
            vT[p][(d0+i)*72 + (n ^ (i<<3))] = (short)f2bf(y[i]);
        }
    };

    stage(0, 0);
    __syncthreads();
    int p = 0;
    for (int ch = 0; ch < 16; ++ch) {
        if (ch < 15) stage(ch+1, p^1);

        // ---- S = D[n][m]: 2 n-tiles, 3-term hi/lo ----
        f32x16 s0, s1;
#pragma unroll
        for (int i = 0; i < 16; ++i) { s0[i] = 0.f; s1[i] = 0.f; }
#pragma unroll
        for (int ks = 0; ks < 4; ++ks) {
            const int dg2 = ks*2 + h;
            const int ofs = dg2*512 + ((l31*8) ^ (dg2*8));
            bf16x8 a0h = *(const bf16x8*)&kfh[p][ofs];
            bf16x8 a0l = *(const bf16x8*)&kfl[p][ofs];
            bf16x8 a1h = *(const bf16x8*)&kfh[p][ofs + 256];
            bf16x8 a1l = *(const bf16x8*)&kfl[p][ofs + 256];
            s0 = MFMA(a0h, pBh[ks], s0);
            s1 = MFMA(a1h, pBh[ks], s1);
            s0 = MFMA(a0l, pBh[ks], s0);
            s1 = MFMA(a1l, pBh[ks], s1);
            s0 = MFMA(a0h, pBl[ks], s0);
            s1 = MFMA(a1h, pBl[ks], s1);
        }

        // ---- w = exp(S - diag), track global max & ksum, all in regs ----
#pragma unroll
        for (int r = 0; r < 16; ++r) {
            const int n0 = PATROW(r, h);
            mloc = fmaxf(mloc, s0[r]);
            const float w0 = __expf(s0[r] - diagl[p][n0]);
            s0[r] = w0; ksacc += w0;
            mloc = fmaxf(mloc, s1[r]);
            const float w1 = __expf(s1[r] - diagl[p][32 + n0]);
            s1[r] = w1; ksacc += w1;
        }

        // ---- in-register repack to A[m][k=n] fragments ----
        bf16x8 wfr[4];
        wfr[0] = repack8<0>(s0, h);
        wfr[1] = repack8<8>(s0, h);
        wfr[2] = repack8<0>(s1, h);
        wfr[3] = repack8<8>(s1, h);

        // ---- ctx GEMM: D[m][e] += w * v ----
#pragma unroll
        for (int ks = 0; ks < 4; ++ks) {
            const int nb = 16*ks + 8*h;
            bf16x8 b0 = *(const bf16x8*)&vT[p][l31*72      + (nb ^ ((l31&7)<<3))];
            bf16x8 b1 = *(const bf16x8*)&vT[p][(l31+32)*72 + (nb ^ ((l31&7)<<3))];
            cacc0 = MFMA(wfr[ks], b0, cacc0);
            cacc1 = MFMA(wfr[ks], b1, cacc1);
        }
        __syncthreads();
        p ^= 1;
    }

    // ---- finals ----
    ksacc += __shfl_xor(ksacc, 32);
    if (h == 0) atomicAdd(&ws[KSUM_OFF + bh*MM + 32*wv + l31], ksacc);

#pragma unroll
    for (int m = 1; m <= 32; m <<= 1) mloc = fmaxf(mloc, __shfl_xor(mloc, m));
    if (lane == 0) atomicMax((unsigned*)&ws[MG_OFF], ford(mloc));

#pragma unroll
    for (int r = 0; r < 16; ++r) {
        const int m = 32*wv + PATROW(r, h);
        ctxred[m*64 + l31]      = cacc0[r];
        ctxred[m*64 + l31 + 32] = cacc1[r];
    }

#pragma unroll
    for (int i = 0; i < 8; ++i) {
        float v = vsacc[i];
        v += __shfl_xor(v, 8); v += __shfl_xor(v, 16); v += __shfl_xor(v, 32);
        vsacc[i] = v;
    }
    if (lane < 8) {
#pragma unroll
        for (int i = 0; i < 8; ++i) vswr[wv][lane*8 + i] = vsacc[i];
    }
    __syncthreads();

    for (int i = tid; i < MM*DD; i += 512)
        atomicAdd(&ws[CTX_OFF + bh*(MM*DD) + i], ctxred[i]);
    if (tid < 64) {
        float s = 0.f;
#pragma unroll
        for (int w = 0; w < 8; ++w) s += vswr[w][tid];
        atomicAdd(&ws[VSUM_OFF + bh*DD + tid], s);
    }
}

// ============================ QUERY ============================
// grid 256 = bh(64) x seg(4); block 512 = 8 waves; 4 chunks x 256 q-rows.
// Barrier-free chunk loop: S = D[m][n] (col n = lane-local q-row), per-row
// max/diag/exp/repack in regs; num GEMM D[n][ecol] with ksum as extra B-column.
__global__ __launch_bounds__(512)
void query_kernel(const float* __restrict__ qg, const float* __restrict__ pg,
                  const float* __restrict__ ws, float* __restrict__ out)
{
    __shared__ __align__(16) short pfh[MM*DD];      // proj hi, frag-grouped
    __shared__ __align__(16) short pfl[MM*DD];      // proj lo
    __shared__ __align__(16) short ctxb[32*96*8];   // (ksg*2+h) x ecol(0..95) x j

    const int tid  = threadIdx.x;
    const int wv   = tid >> 6;
    const int lane = tid & 63;
    const int l31  = lane & 31;
    const int h    = lane >> 5;
    const int bh   = blockIdx.x >> 2;
    const int seg  = blockIdx.x & 3;

    const float mg = ford_inv(*(const unsigned*)&ws[MG_OFF]);
    const float cs = RATIO * __expf(-mg);
    const float ce = RATIO * EPS;

    // proj staging -> frag-grouped LDS
    {
        const int m = tid >> 1, dh = tid & 1;
#pragma unroll
        for (int b = 0; b < 4; ++b) {
            const int d0 = dh*32 + b*8;
            float x[8];
            *(float4*)&x[0] = *(const float4*)(pg + m*64 + d0);
            *(float4*)&x[4] = *(const float4*)(pg + m*64 + d0 + 4);
            bf16x8 hv, lv; split8(x, hv, lv);
            const int g = ((m>>5)*4 + (d0>>4))*2 + ((d0>>3)&1);
            *(bf16x8*)&pfh[(g*32 + (m&31))*8] = hv;
            *(bf16x8*)&pfl[(g*32 + (m&31))*8] = lv;
        }
    }
    // ctx staging: fold cs/ce, bf16, frag-grouped (cols 0..63)
#pragma unroll
    for (int it = 0; it < 4; ++it) {
        const int gid = it*512 + tid;          // 2048 groups
        const int g = gid >> 6, e = gid & 63;  // g = ksg*2+h2
        const int mb = (g>>1)*16 + (g&1)*8;
        const float vs = ws[VSUM_OFF + bh*DD + e];
        union { short s[8]; bf16x8 v; } tmp;
#pragma unroll
        for (int j = 0; j < 8; ++j) {
            const float x = cs*ws[CTX_OFF + bh*(MM*DD) + (mb+j)*64 + e] + ce*vs;
            tmp.s[j] = (short)f2bf(x);
        }
        *(bf16x8*)&ctxb[(g*96 + e)*8] = tmp.v;
    }
    // ksum column (ecol 64) + zero columns (65..95)
    if (tid < 256) {
        const int m = tid;
        const float kt = cs*ws[KSUM_OFF + bh*MM + m] + ce*(float)NSEQ;
        const int g = (m>>4)*2 + ((m>>3)&1);
        ctxb[(g*96 + 64)*8 + (m&7)] = (short)f2bf(kt);
    }
    for (int idx = tid; idx < 32*31*8; idx += 512) {
        const int g = idx / 248, r2 = idx % 248;
        ctxb[(g*96 + 65)*8 + r2] = 0;
    }
    __syncthreads();

    for (int ch = 0; ch < 4; ++ch) {
        const int gn = bh*NSEQ + seg*1024 + ch*256 + wv*32 + l31;

        // q straight from global: B[k=d][col=n] fragments + per-lane diag
        bf16x8 qbh[4], qbl[4];
        float ss = 0.f;
#pragma unroll
        for (int ks = 0; ks < 4; ++ks) {
            const int d0 = 16*ks + 8*h;
            float x[8];
            *(float4*)&x[0] = *(const float4*)(qg + (size_t)gn*64 + d0);
            *(float4*)&x[4] = *(const float4*)(qg + (size_t)gn*64 + d0 + 4);
#pragma unroll
            for (int i = 0; i < 8; ++i) { x[i] *= DN; ss += x[i]*x[i]; }
            split8(x, qbh[ks], qbl[ks]);
        }
        const float diag = 0.5f * (ss + __shfl_xor(ss, 32));

        // S = D[m][n]: 8 m-tiles, 3-term hi/lo
        f32x16 a8[8];
#pragma unroll
        for (int mt = 0; mt < 8; ++mt)
#pragma unroll
            for (int i = 0; i < 16; ++i) a8[mt][i] = 0.f;
#pragma unroll
        for (int ks = 0; ks < 4; ++ks) {
#pragma unroll
            for (int mt = 0; mt < 8; ++mt) {
                const int g = (mt*4 + ks)*2 + h;
                bf16x8 ah = *(const bf16x8*)&pfh[(g*32 + l31)*8];
                bf16x8 al = *(const bf16x8*)&pfl[(g*32 + l31)*8];
                a8[mt] = MFMA(ah, qbh[ks], a8[mt]);
                a8[mt] = MFMA(al, qbh[ks], a8[mt]);
                a8[mt] = MFMA(ah, qbl[ks], a8[mt]);
            }
        }

        // per-row max: lane-local + h-exchange
        float mx = -3e38f;
#pragma unroll
        for (int mt = 0; mt < 8; ++mt)
#pragma unroll
            for (int r = 0; r < 16; ++r) mx = fmaxf(mx, a8[mt][r]);
        mx = fmaxf(mx, __shfl_xor(mx, 32));
        const float c = diag + mx;

        // t = exp(S - c) + eps; repack to A[n][k=m] fragments
        bf16x8 tfr[16];
#pragma unroll
        for (int mt = 0; mt < 8; ++mt) {
#pragma unroll
            for (int r = 0; r < 16; ++r) a8[mt][r] = __expf(a8[mt][r] - c) + EPS;
            tfr[2*mt]   = repack8<0>(a8[mt], h);
            tfr[2*mt+1] = repack8<8>(a8[mt], h);
        }

        // num GEMM: D[n][ecol], ecol tiles {0..31, 32..63, 64..95(den col)}
        f32x16 n0, n1, n2;
#pragma unroll
        for (int i = 0; i < 16; ++i) { n0[i] = 0.f; n1[i] = 0.f; n2[i] = 0.f; }
#pragma unroll
        for (int ks = 0; ks < 16; ++ks) {
            const int g = ks*2 + h;
            bf16x8 b0 = *(const bf16x8*)&ctxb[(g*96 + l31)*8];
            bf16x8 b1 = *(const bf16x8*)&ctxb[(g*96 + l31 + 32)*8];
            bf16x8 b2 = *(const bf16x8*)&ctxb[(g*96 + 64 + l31)*8];
            n0 = MFMA(tfr[ks], b0, n0);
            n1 = MFMA(tfr[ks], b1, n1);
            n2 = MFMA(tfr[ks], b2, n2);
        }

        // den = col 0 of tile 2 (lanes l31==0) -> broadcast; out = num/den
#pragma unroll
        for (int r = 0; r < 16; ++r) {
            const float den = __shfl(n2[r], h ? 32 : 0);
            const float rdn = 1.0f / den;
            const int nn = PATROW(r, h);
            float* op = out + ((size_t)(bh*NSEQ + seg*1024 + ch*256 + wv*32 + nn))*64;
            op[l31]      = n0[r] * rdn;
            op[l31 + 32] = n1[r] * rdn;
        }
    }
}

extern "C" void kernel_launch(void* const* d_in, const int* in_sizes, int n_in,
                              void* d_out, int out_size, void* d_ws, size_t ws_size,
                              hipStream_t stream)
{
    const float* q = (const float*)d_in[0];
    const float* k = (const float*)d_in[1];
    const float* v = (const float*)d_in[2];
    const float* p = (const float*)d_in[3];
    float* ws  = (float*)d_ws;
    float* out = (float*)d_out;

    (void)hipMemsetAsync(d_ws, 0, (size_t)WS_FLOATS * sizeof(float), stream);
    keys_kernel<<<dim3(256), dim3(512), 0, stream>>>(k, v, p, ws);
    query_kernel<<<dim3(256), dim3(512), 0, stream>>>(q, p, ws, out);
}